// Round 7
// baseline (517.916 us; speedup 1.0000x reference)
//
#include <hip/hip_runtime.h>
#include <hip/hip_bf16.h>

// B=4, C=64, H=W=64, D=4, CQ=8. N=H*W=4096, f_qk=32, f_v=256. I/O fp32.
// R7: flash = R6 structure with launch_bounds(256,3) (R6's (256,4) caused
// catastrophic VGPR spill: VGPR_Count 64, WRITE_SIZE 607MB of scratch).
// qkv = R2's proven per-(b,s) compute + in-LDS bf16 transpose so all global
// stores are coalesced uint4.
#define CH 64
#define NN 4096
#define SS 16384

typedef __attribute__((ext_vector_type(4))) short bf16x4;
typedef __attribute__((ext_vector_type(8))) short bf16x8;
typedef __attribute__((ext_vector_type(4))) float f32x4;

// ws layout (ushort elems): Qb (B,N,32) | Kb (B,N,32) | Vt (B,64,256,64)
#define QB_OFF 0
#define KB_OFF 524288
#define VT_OFF 1048576

static __device__ __forceinline__ f32x4 mfma16(bf16x4 a, bf16x4 b, f32x4 c) {
    return __builtin_amdgcn_mfma_f32_16x16x16bf16_1k(a, b, c, 0, 0, 0);
}
static __device__ __forceinline__ ushort bfbits(float x) {
    __hip_bfloat16 h = __float2bfloat16(x);
    return *(ushort*)&h;
}

// ---------------- qkv ----------------
// grid 256 = (b, nt). 256 threads = (n_loc = tid>>2, d = tid&3).
// Compute in regs (R2 structure, ~13 us proven), transpose via LDS,
// all global stores coalesced uint4.
__global__ __launch_bounds__(256) void qkv_kernel(
    const float* __restrict__ x,
    const float* __restrict__ Wq, const float* __restrict__ bq,
    const float* __restrict__ Wk, const float* __restrict__ bk,
    const float* __restrict__ Wv, const float* __restrict__ bv,
    ushort* __restrict__ qb, ushort* __restrict__ kb, ushort* __restrict__ vt)
{
    __shared__ __align__(16) ushort Tv[256 * 72];  // [cv][n], stride 72 (36 KB)
    __shared__ __align__(16) ushort Tq[64 * 40];   // [n][f], stride 40
    __shared__ __align__(16) ushort Tk[64 * 40];

    const int tid = threadIdx.x;
    const int b = blockIdx.x >> 6, nt = blockIdx.x & 63;
    const int nl = tid >> 2, d = tid & 3;

    const float* xp = x + (size_t)b * CH * SS + nt * 256 + tid;
    float xr[CH];
#pragma unroll
    for (int c = 0; c < CH; ++c) xr[c] = xp[(size_t)c * SS];

    // Q and K (8 outputs each); write bf16 into padded LDS tiles
#pragma unroll
    for (int o = 0; o < 8; ++o) {
        float aq = bq[o], ak = bk[o];
#pragma unroll
        for (int c = 0; c < CH; ++c) {
            aq = fmaf(Wq[o * CH + c], xr[c], aq);
            ak = fmaf(Wk[o * CH + c], xr[c], ak);
        }
        Tq[nl * 40 + o * 4 + d] = bfbits(aq);
        Tk[nl * 40 + o * 4 + d] = bfbits(ak);
    }
    // V (64 outputs) -> Tv[cv=o*4+d][n]
#pragma unroll 8
    for (int o = 0; o < CH; ++o) {
        float av = bv[o];
#pragma unroll
        for (int c = 0; c < CH; ++c) av = fmaf(Wv[o * CH + c], xr[c], av);
        Tv[(o * 4 + d) * 72 + nl] = bfbits(av);
    }
    __syncthreads();

    // Q/K readout: thread -> (row n = tid>>2, 16B segment), contiguous global
    {
        const int n = tid >> 2, seg = tid & 3;
        const size_t qa = ((size_t)(b * NN + nt * 64 + n)) * 32 + seg * 8;
        *(uint4*)(qb + qa) = *(const uint4*)&Tq[n * 40 + seg * 8];
        *(uint4*)(kb + qa) = *(const uint4*)&Tk[n * 40 + seg * 8];
    }
    // V readout: wave w covers cv in [64w,64w+64); inst j covers 8 rows x 128B
    const int w = tid >> 6, l = tid & 63;
    ushort* vout = vt + ((size_t)(b * 64 + nt) * 256) * 64;
#pragma unroll
    for (int j = 0; j < 8; ++j) {
        int cv = 64 * w + 8 * j + (l >> 3);
        int h = l & 7;
        *(uint4*)(vout + (size_t)cv * 64 + h * 8) =
            *(const uint4*)&Tv[cv * 72 + h * 8];
    }
}

// ---------------- flash ----------------
// grid 1024 = (b, 32-row Q-tile rq, cv-half). 256 threads = 4 waves.
// Wave w owns m-slice [16w,16w+16) per 64-wide K-tile (m-split PV, P in regs).
// launch_bounds(256,3): 168-VGPR budget fits ~130 live regs, 3 blocks/CU.
__global__ __launch_bounds__(256, 3) void flash_kernel(
    const ushort* __restrict__ qb, const ushort* __restrict__ kb,
    const ushort* __restrict__ vt, const float* __restrict__ x3d,
    const float* __restrict__ gptr, float* __restrict__ out)
{
    __shared__ __align__(16) ushort Vls[2][128 * 72];  // [cv'][m], stride 72
    __shared__ float lbuf[8 * 16];

    const int tid = threadIdx.x;
    const int b   = blockIdx.x >> 8;
    const int rq  = (blockIdx.x >> 1) & 127;
    const int cvh = blockIdx.x & 1;
    const int r0  = rq * 32;
    const int w = tid >> 6, lane = tid & 63, q = lane >> 4, l15 = lane & 15;

    // Q B-frags (16x16x32): B[f=8q+j][r=16rt+l15]
    bf16x8 Qf[2];
#pragma unroll
    for (int rt = 0; rt < 2; ++rt)
        Qf[rt] = *(const bf16x8*)(qb + (size_t)(b * NN + r0 + 16 * rt + l15) * 32 + 8 * q);

    f32x4 acc[8][2];
#pragma unroll
    for (int i = 0; i < 8; ++i)
#pragma unroll
        for (int j = 0; j < 2; ++j) acc[i][j] = (f32x4){0.f, 0.f, 0.f, 0.f};
    float l_acc[2] = {0.f, 0.f};

    // K A-frags direct from global: wave w reads rows m = kt*64 + 16w + l15
    const ushort* kgl = kb + (size_t)b * NN * 32 + (16 * w + l15) * 32 + 8 * q;
    bf16x8 Ka_cur = *(const bf16x8*)(kgl);
    bf16x8 Ka_nxt = *(const bf16x8*)(kgl + 2048);

    const ushort* vgl = vt + ((size_t)b * 64 * 256 + 128 * cvh) * 64;
    uint4 vst[4];
#pragma unroll
    for (int i = 0; i < 4; ++i)
        vst[i] = *(const uint4*)(vgl + (size_t)(i * 256 + tid) * 8);
#pragma unroll
    for (int i = 0; i < 4; ++i) {                  // tile 0 -> buf 0
        int i4 = i * 256 + tid;
        *(uint4*)(&Vls[0][(i4 >> 3) * 72 + (i4 & 7) * 8]) = vst[i];
    }
#pragma unroll
    for (int i = 0; i < 4; ++i)                    // prefetch tile 1
        vst[i] = *(const uint4*)(vgl + 16384 + (size_t)(i * 256 + tid) * 8);

    for (int kt = 0; kt < 64; ++kt) {
        __syncthreads();   // buf[kt&1] staged; everyone done reading buf[(kt+1)&1]
        if (kt < 63) {
#pragma unroll
            for (int i = 0; i < 4; ++i) {
                int i4 = i * 256 + tid;
                *(uint4*)(&Vls[(kt + 1) & 1][(i4 >> 3) * 72 + (i4 & 7) * 8]) = vst[i];
            }
            if (kt < 62) {
#pragma unroll
                for (int i = 0; i < 4; ++i)
                    vst[i] = *(const uint4*)(vgl + (size_t)(kt + 2) * 16384
                                             + (size_t)(i * 256 + tid) * 8);
            }
        }
        bf16x8 Ka = Ka_cur;
        Ka_cur = Ka_nxt;
        if (kt < 62) Ka_nxt = *(const bf16x8*)(kgl + (size_t)(kt + 2) * 2048);

        // S^T slice: D[m=4q+reg][r=16rt+l15]
        f32x4 S[2];
#pragma unroll
        for (int rt = 0; rt < 2; ++rt)
            S[rt] = __builtin_amdgcn_mfma_f32_16x16x32_bf16(
                Ka, Qf[rt], (f32x4){0.f, 0.f, 0.f, 0.f}, 0, 0, 0);

        // exp (no max-sub: |s| <~ 9), l partial; P stays in registers
        // (C-layout (m=4q+reg, r=l15) == 16x16x16 B-layout (k=4q+j, n=l15))
        bf16x4 Pb[2];
#pragma unroll
        for (int rt = 0; rt < 2; ++rt) {
            float e0 = __expf(S[rt][0]), e1 = __expf(S[rt][1]);
            float e2 = __expf(S[rt][2]), e3 = __expf(S[rt][3]);
            l_acc[rt] += (e0 + e1) + (e2 + e3);
            bf16x4 p;
            p[0] = (short)bfbits(e0); p[1] = (short)bfbits(e1);
            p[2] = (short)bfbits(e2); p[3] = (short)bfbits(e3);
            Pb[rt] = p;
        }

        // partial O^T: A[cv=16cvt+l15][k=4q+j] from Vls at wave's m-slice
        const ushort* vb = Vls[kt & 1] + 16 * w + 4 * q;
#pragma unroll
        for (int cvt = 0; cvt < 8; ++cvt) {
            bf16x4 Va = *(const bf16x4*)(vb + (16 * cvt + l15) * 72);
#pragma unroll
            for (int rt = 0; rt < 2; ++rt)
                acc[cvt][rt] = mfma16(Va, Pb[rt], acc[cvt][rt]);
        }
    }

    // l: reduce over quads (shfl) then across 4 waves (lbuf)
#pragma unroll
    for (int rt = 0; rt < 2; ++rt) {
        float v = l_acc[rt];
        v += __shfl_xor(v, 16);
        v += __shfl_xor(v, 32);
        if (lane < 16) lbuf[(w * 2 + rt) * 16 + lane] = v;
    }
    __syncthreads();   // also: last Vls read done -> Obuf may alias Vls
    const int rte = w & 1;
    const float linv = 1.f / (lbuf[(0 + rte) * 16 + l15] + lbuf[(2 + rte) * 16 + l15] +
                              lbuf[(4 + rte) * 16 + l15] + lbuf[(6 + rte) * 16 + l15]);
    const float gl = gptr[0] * linv;

    // cross-wave O reduction (4 m-slices) in 8 cvt chunks, Obuf aliases Vls
    f32x4* Obuf = (f32x4*)&Vls[0][0];   // 8*64 f32x4 = 8 KB
#pragma unroll
    for (int cvt = 0; cvt < 8; ++cvt) {
        __syncthreads();
        Obuf[(w * 2 + 0) * 64 + lane] = acc[cvt][0];
        Obuf[(w * 2 + 1) * 64 + lane] = acc[cvt][1];
        __syncthreads();
        if (w < 2) {   // waves 0,1 store rt = w
            f32x4 o = Obuf[(0 + w) * 64 + lane] + Obuf[(2 + w) * 64 + lane] +
                      Obuf[(4 + w) * 64 + lane] + Obuf[(6 + w) * 64 + lane];
            // cv = 128cvh + 16cvt + 4q + reg -> c = 32cvh + 4cvt + q, d = reg
            size_t addr = ((size_t)(b * CH + 32 * cvh + 4 * cvt + q) * NN
                           + (r0 + 16 * w + l15)) * 4;
            float4 xr = *(const float4*)(x3d + addr);
            float4 res;
            res.x = fmaf(gl, o[0], xr.x);
            res.y = fmaf(gl, o[1], xr.y);
            res.z = fmaf(gl, o[2], xr.z);
            res.w = fmaf(gl, o[3], xr.w);
            *(float4*)(out + addr) = res;
        }
    }
}

extern "C" void kernel_launch(void* const* d_in, const int* in_sizes, int n_in,
                              void* d_out, int out_size, void* d_ws, size_t ws_size,
                              hipStream_t stream)
{
    const float* x2d = (const float*)d_in[0];
    const float* x3d = (const float*)d_in[1];
    const float* Wq  = (const float*)d_in[2];
    const float* bq  = (const float*)d_in[3];
    const float* Wk  = (const float*)d_in[4];
    const float* bk  = (const float*)d_in[5];
    const float* Wv  = (const float*)d_in[6];
    const float* bv  = (const float*)d_in[7];
    const float* gma = (const float*)d_in[8];

    ushort* wsb = (ushort*)d_ws;

    qkv_kernel<<<256, 256, 0, stream>>>(x2d, Wq, bq, Wk, bk, Wv, bv,
                                        wsb + QB_OFF, wsb + KB_OFF, wsb + VT_OFF);
    flash_kernel<<<1024, 256, 0, stream>>>(wsb + QB_OFF, wsb + KB_OFF, wsb + VT_OFF,
                                           x3d, gma, (float*)d_out);
}

// Round 8
// 334.180 us; speedup vs baseline: 1.5498x; 1.5498x over previous
//
#include <hip/hip_runtime.h>
#include <hip/hip_bf16.h>

// B=4, C=64, H=W=64, D=4, CQ=8. N=H*W=4096, f_qk=32, f_v=256. I/O fp32.
// R8: K-pair PV. Two 64-m K-tiles per iteration; the pair of S^T C-layouts
// (m=4q+reg per tile) concatenates into one 16x16x32 B-operand (k=8q+j), so
// PV uses mfma32 throughout (40 mfma32/pair vs R5's 8 mfma32 + 64 mfma16).
// V global layout stores m in interleaved slots: slot = 32*w' + 8*q + 4*t + r
// for m = t*64 + 16*w' + 4*q + r, so flash A-frags are single ds_read_b128.
// Register budget: acc[8][4]=128 AGPR + ~116 arch <= 256 (2 waves/SIMD, the
// proven no-spill point; R6/R7 showed tighter bounds => catastrophic spill).
#define CH 64
#define NN 4096
#define SS 16384

typedef __attribute__((ext_vector_type(8))) short bf16x8;
typedef __attribute__((ext_vector_type(4))) float f32x4;

// ws layout (ushort elems): Qb (B,N,32) | Kb (B,N,32) |
// Vt [b][sup:32][cv:256][row:144] (128 data slots + 16 pad per row)
#define QB_OFF 0
#define KB_OFF 524288
#define VT_OFF 1048576

static __device__ __forceinline__ ushort bfbits(float x) {
    __hip_bfloat16 h = __float2bfloat16(x);
    return *(ushort*)&h;
}

// ---------------- qkv ----------------
// grid 256 = (b, nt of 64 n). 256 threads = (nl = tid>>2, d = tid&3).
// Compute per-thread in regs; LDS transpose; coalesced readout.
__global__ __launch_bounds__(256) void qkv_kernel(
    const float* __restrict__ x,
    const float* __restrict__ Wq, const float* __restrict__ bq,
    const float* __restrict__ Wk, const float* __restrict__ bk,
    const float* __restrict__ Wv, const float* __restrict__ bv,
    ushort* __restrict__ qb, ushort* __restrict__ kb, ushort* __restrict__ vt)
{
    __shared__ __align__(16) ushort Tv[256 * 72];  // [cv][nl]
    __shared__ __align__(16) ushort Tq[64 * 40];   // [nl][f]
    __shared__ __align__(16) ushort Tk[64 * 40];

    const int tid = threadIdx.x;
    const int b = blockIdx.x >> 6, nt = blockIdx.x & 63;
    const int nl = tid >> 2, d = tid & 3;

    const float* xp = x + (size_t)b * CH * SS + nt * 256 + tid;
    float xr[CH];
#pragma unroll
    for (int c = 0; c < CH; ++c) xr[c] = xp[(size_t)c * SS];

#pragma unroll
    for (int o = 0; o < 8; ++o) {
        float aq = bq[o], ak = bk[o];
#pragma unroll
        for (int c = 0; c < CH; ++c) {
            aq = fmaf(Wq[o * CH + c], xr[c], aq);
            ak = fmaf(Wk[o * CH + c], xr[c], ak);
        }
        Tq[nl * 40 + o * 4 + d] = bfbits(aq);
        Tk[nl * 40 + o * 4 + d] = bfbits(ak);
    }
#pragma unroll 8
    for (int o = 0; o < CH; ++o) {
        float av = bv[o];
#pragma unroll
        for (int c = 0; c < CH; ++c) av = fmaf(Wv[o * CH + c], xr[c], av);
        Tv[(o * 4 + d) * 72 + nl] = bfbits(av);
    }
    __syncthreads();

    // Q/K readout: row n = tid>>2, 16B segment = tid&3 -> contiguous global
    {
        const int n = tid >> 2, seg = tid & 3;
        const size_t qa = ((size_t)(b * NN + nt * 64 + n)) * 32 + seg * 8;
        *(uint4*)(qb + qa) = *(const uint4*)&Tq[n * 40 + seg * 8];
        *(uint4*)(kb + qa) = *(const uint4*)&Tk[n * 40 + seg * 8];
    }
    // V readout into interleaved-slot layout.
    // block covers tile t = nt&1 of super-tile sup = nt>>1 (m = n&127).
    // nl run {16w'+4q .. +3} -> global slots {32w'+8q+4t .. +3} (uint2 = 4 us)
    const int w = tid >> 6, l = tid & 63;
    const int sup = nt >> 1, t = nt & 1;
    const int rn = l & 15, c4 = l >> 4;
    const int nl0 = 16 * (rn >> 2) + 4 * (rn & 3);
    const int sl0 = 32 * (rn >> 2) + 8 * (rn & 3) + 4 * t;
    ushort* vout = vt + ((size_t)(b * 32 + sup) * 256) * 144;
#pragma unroll
    for (int i = 0; i < 16; ++i) {
        int cv = 64 * w + 4 * i + c4;
        *(uint2*)(vout + (size_t)cv * 144 + sl0) = *(const uint2*)&Tv[cv * 72 + nl0];
    }
}

// ---------------- flash ----------------
// grid 512 = (b, 64-row Q-tile, cv-half). 256 threads = 4 waves.
// Wave w owns m-slice [16w,16w+16) of each tile; pair = 2 tiles = 32 k.
__global__ __launch_bounds__(256, 2) void flash_kernel(
    const ushort* __restrict__ qb, const ushort* __restrict__ kb,
    const ushort* __restrict__ vt, const float* __restrict__ x3d,
    const float* __restrict__ gptr, float* __restrict__ out)
{
    __shared__ __align__(16) ushort Vls[2][128 * 144];  // [cv'][slot], dbuf
    __shared__ float lbuf[4 * 4 * 16];

    const int tid = threadIdx.x;
    const int b   = blockIdx.x >> 7;
    const int rem = blockIdx.x & 127;
    const int r0  = (rem >> 1) << 6;
    const int cvh = rem & 1;
    const int w = tid >> 6, lane = tid & 63, q = lane >> 4, l15 = lane & 15;

    // Q B-frags (16x16x32): B[f=8q+j][r=16rt+l15]
    bf16x8 Qf[4];
#pragma unroll
    for (int rt = 0; rt < 4; ++rt)
        Qf[rt] = *(const bf16x8*)(qb + (size_t)(b * NN + r0 + 16 * rt + l15) * 32 + 8 * q);

    f32x4 acc[8][4];
#pragma unroll
    for (int i = 0; i < 8; ++i)
#pragma unroll
        for (int j = 0; j < 4; ++j) acc[i][j] = (f32x4){0.f, 0.f, 0.f, 0.f};
    float l_acc[4] = {0.f, 0.f, 0.f, 0.f};

    // K rows for wave w, tile mt: kb[(mt*64 + 16w + l15)*32 + 8q]
    const ushort* kgl = kb + (size_t)b * NN * 32 + (16 * w + l15) * 32 + 8 * q;

    // V stream: pair pt occupies 36,864 ushort per sup; block's 128-cv chunk
    // is 128*144 = 18,432 ushort contiguous.
    const ushort* vgl = vt + ((size_t)(b * 32) * 256 + 128 * cvh) * 144;

    uint4 vst[9];
#pragma unroll
    for (int i = 0; i < 9; ++i)                    // pair 0
        vst[i] = *(const uint4*)(vgl + (size_t)(i * 256 + tid) * 8);
#pragma unroll
    for (int i = 0; i < 9; ++i)
        *(uint4*)((ushort*)Vls[0] + (i * 256 + tid) * 8) = vst[i];
#pragma unroll
    for (int i = 0; i < 9; ++i)                    // prefetch pair 1
        vst[i] = *(const uint4*)(vgl + 36864 + (size_t)(i * 256 + tid) * 8);

    for (int pt = 0; pt < 32; ++pt) {
        __syncthreads();   // buf[pt&1] staged; buf[pt^1] readers done
        // issue K loads FIRST: vmcnt for S^T then waits only on these two
        bf16x8 Ka0 = *(const bf16x8*)(kgl + (size_t)(2 * pt) * 2048);
        bf16x8 Ka1 = *(const bf16x8*)(kgl + (size_t)(2 * pt + 1) * 2048);
        if (pt < 31) {
#pragma unroll
            for (int i = 0; i < 9; ++i)
                *(uint4*)((ushort*)Vls[(pt + 1) & 1] + (i * 256 + tid) * 8) = vst[i];
            if (pt < 30) {
#pragma unroll
                for (int i = 0; i < 9; ++i)
                    vst[i] = *(const uint4*)(vgl + (size_t)(pt + 2) * 36864
                                             + (size_t)(i * 256 + tid) * 8);
            }
        }

        // S^T slices: D[m=4q+reg][r=16rt+l15] for tiles 0,1 of the pair
        f32x4 S0[4], S1[4];
#pragma unroll
        for (int rt = 0; rt < 4; ++rt)
            S0[rt] = __builtin_amdgcn_mfma_f32_16x16x32_bf16(
                Ka0, Qf[rt], (f32x4){0.f, 0.f, 0.f, 0.f}, 0, 0, 0);
#pragma unroll
        for (int rt = 0; rt < 4; ++rt)
            S1[rt] = __builtin_amdgcn_mfma_f32_16x16x32_bf16(
                Ka1, Qf[rt], (f32x4){0.f, 0.f, 0.f, 0.f}, 0, 0, 0);

        // exp (no max-sub: |s| <~ 9); concat pair C-layouts -> 16x16x32 B-frag
        bf16x8 Pb[4];
#pragma unroll
        for (int rt = 0; rt < 4; ++rt) {
            float e0 = __expf(S0[rt][0]), e1 = __expf(S0[rt][1]);
            float e2 = __expf(S0[rt][2]), e3 = __expf(S0[rt][3]);
            float f0 = __expf(S1[rt][0]), f1 = __expf(S1[rt][1]);
            float f2 = __expf(S1[rt][2]), f3 = __expf(S1[rt][3]);
            l_acc[rt] += ((e0 + e1) + (e2 + e3)) + ((f0 + f1) + (f2 + f3));
            bf16x8 p;
            p[0] = (short)bfbits(e0); p[1] = (short)bfbits(e1);
            p[2] = (short)bfbits(e2); p[3] = (short)bfbits(e3);
            p[4] = (short)bfbits(f0); p[5] = (short)bfbits(f1);
            p[6] = (short)bfbits(f2); p[7] = (short)bfbits(f3);
            Pb[rt] = p;
        }

        // PV: A[cv=16cvt+l15][k=8q+j] = one ds_read_b128 from slots 32w+8q..
        const ushort* vb = Vls[pt & 1] + 32 * w + 8 * q;
#pragma unroll
        for (int cvt = 0; cvt < 8; ++cvt) {
            bf16x8 Va = *(const bf16x8*)(vb + (16 * cvt + l15) * 144);
#pragma unroll
            for (int rt = 0; rt < 4; ++rt)
                acc[cvt][rt] = __builtin_amdgcn_mfma_f32_16x16x32_bf16(
                    Va, Pb[rt], acc[cvt][rt], 0, 0, 0);
        }
    }

    // l: reduce over quads (shfl) then across 4 waves (lbuf)
#pragma unroll
    for (int rt = 0; rt < 4; ++rt) {
        float v = l_acc[rt];
        v += __shfl_xor(v, 16);
        v += __shfl_xor(v, 32);
        if (lane < 16) lbuf[(w * 4 + rt) * 16 + lane] = v;
    }
    __syncthreads();
    // this thread's epilogue rows are r = 16w + l15 (rt = w)
    const float linv = 1.f / (lbuf[(0 + w) * 16 + l15] + lbuf[(4 + w) * 16 + l15] +
                              lbuf[(8 + w) * 16 + l15] + lbuf[(12 + w) * 16 + l15]);
    const float gl = gptr[0] * linv;

    // cross-wave O reduction in 8 cvt chunks; Obuf aliases Vls[0] (20.5 KB)
    f32x4* Obuf = (f32x4*)&Vls[0][0];
#pragma unroll
    for (int cvt = 0; cvt < 8; ++cvt) {
        __syncthreads();
#pragma unroll
        for (int rt = 0; rt < 4; ++rt)
            Obuf[(w * 64 + lane) * 5 + rt] = acc[cvt][rt];
        __syncthreads();
        f32x4 o = Obuf[lane * 5 + w];
        o += Obuf[(64 + lane) * 5 + w];
        o += Obuf[(128 + lane) * 5 + w];
        o += Obuf[(192 + lane) * 5 + w];
        // cv = 128cvh + 16cvt + 4q + reg -> c = 32cvh + 4cvt + q, d = reg
        size_t addr = ((size_t)(b * CH + 32 * cvh + 4 * cvt + q) * NN
                       + (r0 + 16 * w + l15)) * 4;
        float4 xr = *(const float4*)(x3d + addr);
        float4 res;
        res.x = fmaf(gl, o[0], xr.x);
        res.y = fmaf(gl, o[1], xr.y);
        res.z = fmaf(gl, o[2], xr.z);
        res.w = fmaf(gl, o[3], xr.w);
        *(float4*)(out + addr) = res;
    }
}

extern "C" void kernel_launch(void* const* d_in, const int* in_sizes, int n_in,
                              void* d_out, int out_size, void* d_ws, size_t ws_size,
                              hipStream_t stream)
{
    const float* x2d = (const float*)d_in[0];
    const float* x3d = (const float*)d_in[1];
    const float* Wq  = (const float*)d_in[2];
    const float* bq  = (const float*)d_in[3];
    const float* Wk  = (const float*)d_in[4];
    const float* bk  = (const float*)d_in[5];
    const float* Wv  = (const float*)d_in[6];
    const float* bv  = (const float*)d_in[7];
    const float* gma = (const float*)d_in[8];

    ushort* wsb = (ushort*)d_ws;

    qkv_kernel<<<256, 256, 0, stream>>>(x2d, Wq, bq, Wk, bk, Wv, bv,
                                        wsb + QB_OFF, wsb + KB_OFF, wsb + VT_OFF);
    flash_kernel<<<512, 256, 0, stream>>>(wsb + QB_OFF, wsb + KB_OFF, wsb + VT_OFF,
                                          x3d, gma, (float*)d_out);
}

// Round 10
// 171.522 us; speedup vs baseline: 3.0195x; 1.9483x over previous
//
#include <hip/hip_runtime.h>
#include <hip/hip_bf16.h>

// B=4, C=64, H=W=64, D=4, CQ=8. N=H*W=4096, f_qk=32, f_v=256. I/O fp32.
// R10 = R9 with the two qkv readout-halving bugs fixed (Q/K rows need 4 uint4
// chunks not 2; V rows need 16 not 8 -- R9 left the upper halves 0xAA poison,
// costing absmax 0.137). Flash unchanged: V staged via global_load_lds
// (zero staging VGPRs; R6/R7/R8 spilled via register V-prefetch), K-pair PV
// (all 16x16x32 MFMA), P in registers (QK C-layout == PV B-layout).
#define CH 64
#define NN 4096
#define SS 16384

typedef __attribute__((ext_vector_type(8))) short bf16x8;
typedef __attribute__((ext_vector_type(4))) float f32x4;

// ws layout (ushort elems): Qb (B,N,32) | Kb (B,N,32) |
// Vt [b][sup:32][cv:256][slot:144] (128 data slots + 16 pad)
#define QB_OFF 0
#define KB_OFF 524288
#define VT_OFF 1048576

static __device__ __forceinline__ ushort bfbits(float x) {
    __hip_bfloat16 h = __float2bfloat16(x);
    return *(ushort*)&h;
}

static __device__ __forceinline__ void gld_lds16(const ushort* g, ushort* l) {
    __builtin_amdgcn_global_load_lds(
        (const __attribute__((address_space(1))) void*)g,
        (__attribute__((address_space(3))) void*)l, 16, 0, 0);
}

// ---------------- qkv ----------------
template<int NO>
static __device__ __forceinline__ void dots(
    const float* __restrict__ W, const float* __restrict__ bias, int o0,
    const float* xr, float* A)
{
#pragma unroll
    for (int i = 0; i < NO; ++i) A[i] = bias[o0 + i];
#pragma unroll
    for (int c = 0; c < CH; ++c) {
        float xv = xr[c];
#pragma unroll
        for (int i = 0; i < NO; ++i)
            A[i] = fmaf(W[(o0 + i) * CH + c], xv, A[i]);
    }
}

// grid 512 = (b, sup in [0,32), og in [0,4)). 256 threads = (nl = tid>>2, d).
// Block covers both 64-n tiles of super-tile sup (t = 0,1), og splits outputs:
// og0: q8 + v[0:12); og1: k8 + v[12:24); og2: v[24:44); og3: v[44:64).
__global__ __launch_bounds__(256) void qkv_kernel(
    const float* __restrict__ x,
    const float* __restrict__ Wq, const float* __restrict__ bq,
    const float* __restrict__ Wk, const float* __restrict__ bk,
    const float* __restrict__ Wv, const float* __restrict__ bv,
    ushort* __restrict__ qb, ushort* __restrict__ kb, ushort* __restrict__ vt)
{
    __shared__ __align__(16) ushort Tqk[128 * 40];  // [n_loc][f], q or k
    __shared__ __align__(16) ushort Tv[80 * 144];   // [cv_loc][slot]

    const int blk = blockIdx.x;
    const int b = blk >> 7, sup = (blk >> 2) & 31, og = blk & 3;
    const int tid = threadIdx.x;
    const int nl = tid >> 2, d = tid & 3;

    const int vcnt = (og < 2) ? 12 : 20;
    const int vo0 = (og == 0) ? 0 : (og == 1) ? 12 : (og == 2) ? 24 : 44;

    const float* xb = x + (size_t)b * CH * SS + sup * 512;

#pragma unroll
    for (int t = 0; t < 2; ++t) {
        const float* xp = xb + t * 256 + tid;
        float xr[CH];
#pragma unroll
        for (int c = 0; c < CH; ++c) xr[c] = xp[(size_t)c * SS];

        // flash pair-interleave: m_loc = nl of tile t -> slot
        const int slot = 32 * (nl >> 4) + 8 * ((nl >> 2) & 3) + 4 * t + (nl & 3);

        if (og == 0) {
            float A[8];
            dots<8>(Wq, bq, 0, xr, A);
#pragma unroll
            for (int o = 0; o < 8; ++o)
                Tqk[(t * 64 + nl) * 40 + o * 4 + d] = bfbits(A[o]);
        } else if (og == 1) {
            float A[8];
            dots<8>(Wk, bk, 0, xr, A);
#pragma unroll
            for (int o = 0; o < 8; ++o)
                Tqk[(t * 64 + nl) * 40 + o * 4 + d] = bfbits(A[o]);
        }
        float V[20];
        if (og < 2) dots<12>(Wv, bv, vo0, xr, V);
        else        dots<20>(Wv, bv, vo0, xr, V);
#pragma unroll
        for (int j = 0; j < 20; ++j)
            if (j < vcnt)
                Tv[(j * 4 + d) * 144 + slot] = bfbits(V[j]);
    }
    __syncthreads();

    // Q/K readout: 128 rows x 32 ushorts = 512 uint4 chunks, 2 per thread
    if (og < 2) {
        ushort* dst = (og == 0 ? qb : kb);
#pragma unroll
        for (int jj = 0; jj < 2; ++jj) {
            int idx = jj * 256 + tid;
            int row = idx >> 2, seg = idx & 3;
            *(uint4*)(dst + ((size_t)(b * NN + sup * 128 + row)) * 32 + seg * 8)
                = *(const uint4*)&Tqk[row * 40 + seg * 8];
        }
    }
    // V readout: vcnt*4 rows x 128 data slots = vcnt*64 uint4 chunks
    const int nchunks = vcnt * 64;   // 768 (og<2) or 1280 (og>=2)
    ushort* vout = vt + ((size_t)((b * 32 + sup) * 256 + vo0 * 4)) * 144;
#pragma unroll
    for (int j = 0; j < 5; ++j) {
        int idx = j * 256 + tid;
        if (idx < nchunks) {
            int row = idx >> 4, seg = idx & 15;
            *(uint4*)(vout + (size_t)row * 144 + seg * 8)
                = *(const uint4*)&Tv[row * 144 + seg * 8];
        }
    }
}

// ---------------- flash ----------------
// grid 512 = (b, 64-row Q-tile, cv-half). 256 threads = 4 waves.
// Wave w owns m-slice [16w,16w+16) of each 64-m tile; pair = 2 tiles = 32 k.
// V staged async global->LDS (no VGPRs); K 1-pair-ahead register prefetch.
__global__ __launch_bounds__(256, 2) void flash_kernel(
    const ushort* __restrict__ qb, const ushort* __restrict__ kb,
    const ushort* __restrict__ vt, const float* __restrict__ x3d,
    const float* __restrict__ gptr, float* __restrict__ out)
{
    __shared__ __align__(16) ushort Vls[2][128 * 144];  // [cv'][slot], dbuf
    __shared__ float lbuf[4 * 4 * 16];

    const int tid = threadIdx.x;
    const int b   = blockIdx.x >> 7;
    const int rem = blockIdx.x & 127;
    const int r0  = (rem >> 1) << 6;
    const int cvh = rem & 1;
    const int w = tid >> 6, lane = tid & 63, q = lane >> 4, l15 = lane & 15;

    // Q B-frags (16x16x32): B[f=8q+j][r=16rt+l15]
    bf16x8 Qf[4];
#pragma unroll
    for (int rt = 0; rt < 4; ++rt)
        Qf[rt] = *(const bf16x8*)(qb + (size_t)(b * NN + r0 + 16 * rt + l15) * 32 + 8 * q);

    f32x4 acc[8][4];
#pragma unroll
    for (int i = 0; i < 8; ++i)
#pragma unroll
        for (int j = 0; j < 4; ++j) acc[i][j] = (f32x4){0.f, 0.f, 0.f, 0.f};
    float l_acc[4] = {0.f, 0.f, 0.f, 0.f};

    // K rows for wave w, tile mt: kb[(mt*64 + 16w + l15)*32 + 8q]
    const ushort* kgl = kb + (size_t)b * NN * 32 + (16 * w + l15) * 32 + 8 * q;

    // V stream: block's 128-cv half of each sup = 128*144 ushorts contiguous
    const ushort* vgl = vt + ((size_t)(b * 32) * 256 + 128 * cvh) * 144;

    // async stage pair 0 -> buf 0 (wave-uniform base + lane*16: valid DMA)
#pragma unroll
    for (int i = 0; i < 9; ++i)
        gld_lds16(vgl + (size_t)(i * 256 + tid) * 8,
                  (ushort*)Vls[0] + (i * 256 + tid) * 8);

    bf16x8 Kn0 = *(const bf16x8*)(kgl);
    bf16x8 Kn1 = *(const bf16x8*)(kgl + 2048);

    for (int pt = 0; pt < 32; ++pt) {
        __syncthreads();   // vmcnt drained: buf[pt&1] DMA landed; buf[pt^1] readers done
        if (pt < 31) {     // async prefetch pair pt+1 into the other buffer
            const ushort* src = vgl + (size_t)(pt + 1) * 36864;
            ushort* dst = (ushort*)Vls[(pt + 1) & 1];
#pragma unroll
            for (int i = 0; i < 9; ++i)
                gld_lds16(src + (size_t)(i * 256 + tid) * 8, dst + (i * 256 + tid) * 8);
        }
        bf16x8 Ka0 = Kn0, Ka1 = Kn1;   // loaded last iter, resolved by barrier
        if (pt < 31) {
            Kn0 = *(const bf16x8*)(kgl + (size_t)(2 * pt + 2) * 2048);
            Kn1 = *(const bf16x8*)(kgl + (size_t)(2 * pt + 3) * 2048);
        }

        // S^T slices: D[m=4q+reg][r=16rt+l15] for tiles 0,1 of the pair
        f32x4 S0[4], S1[4];
#pragma unroll
        for (int rt = 0; rt < 4; ++rt)
            S0[rt] = __builtin_amdgcn_mfma_f32_16x16x32_bf16(
                Ka0, Qf[rt], (f32x4){0.f, 0.f, 0.f, 0.f}, 0, 0, 0);
#pragma unroll
        for (int rt = 0; rt < 4; ++rt)
            S1[rt] = __builtin_amdgcn_mfma_f32_16x16x32_bf16(
                Ka1, Qf[rt], (f32x4){0.f, 0.f, 0.f, 0.f}, 0, 0, 0);

        // exp (no max-sub: |s| <~ 9); concat pair C-layouts -> 16x16x32 B-frag
        bf16x8 Pb[4];
#pragma unroll
        for (int rt = 0; rt < 4; ++rt) {
            float e0 = __expf(S0[rt][0]), e1 = __expf(S0[rt][1]);
            float e2 = __expf(S0[rt][2]), e3 = __expf(S0[rt][3]);
            float f0 = __expf(S1[rt][0]), f1 = __expf(S1[rt][1]);
            float f2 = __expf(S1[rt][2]), f3 = __expf(S1[rt][3]);
            l_acc[rt] += ((e0 + e1) + (e2 + e3)) + ((f0 + f1) + (f2 + f3));
            bf16x8 p;
            p[0] = (short)bfbits(e0); p[1] = (short)bfbits(e1);
            p[2] = (short)bfbits(e2); p[3] = (short)bfbits(e3);
            p[4] = (short)bfbits(f0); p[5] = (short)bfbits(f1);
            p[6] = (short)bfbits(f2); p[7] = (short)bfbits(f3);
            Pb[rt] = p;
        }

        // PV: A[cv=16cvt+l15][k=8q+j] = one ds_read_b128 (slots 32w+8q..+7)
        const ushort* vb = Vls[pt & 1] + 32 * w + 8 * q;
#pragma unroll
        for (int cvt = 0; cvt < 8; ++cvt) {
            bf16x8 Va = *(const bf16x8*)(vb + (16 * cvt + l15) * 144);
#pragma unroll
            for (int rt = 0; rt < 4; ++rt)
                acc[cvt][rt] = __builtin_amdgcn_mfma_f32_16x16x32_bf16(
                    Va, Pb[rt], acc[cvt][rt], 0, 0, 0);
        }
    }

    // l: reduce over quads (shfl) then across 4 waves (lbuf)
#pragma unroll
    for (int rt = 0; rt < 4; ++rt) {
        float v = l_acc[rt];
        v += __shfl_xor(v, 16);
        v += __shfl_xor(v, 32);
        if (lane < 16) lbuf[(w * 4 + rt) * 16 + lane] = v;
    }
    __syncthreads();
    // this thread's epilogue rows are r = 16w + l15 (rt = w)
    const float linv = 1.f / (lbuf[(0 + w) * 16 + l15] + lbuf[(4 + w) * 16 + l15] +
                              lbuf[(8 + w) * 16 + l15] + lbuf[(12 + w) * 16 + l15]);
    const float gl = gptr[0] * linv;

    // cross-wave O reduction in 8 cvt chunks; Obuf aliases Vls[0]
    f32x4* Obuf = (f32x4*)&Vls[0][0];
#pragma unroll
    for (int cvt = 0; cvt < 8; ++cvt) {
        __syncthreads();
#pragma unroll
        for (int rt = 0; rt < 4; ++rt)
            Obuf[(w * 64 + lane) * 5 + rt] = acc[cvt][rt];
        __syncthreads();
        f32x4 o = Obuf[lane * 5 + w];
        o += Obuf[(64 + lane) * 5 + w];
        o += Obuf[(128 + lane) * 5 + w];
        o += Obuf[(192 + lane) * 5 + w];
        // cv = 128cvh + 16cvt + 4q + reg -> c = 32cvh + 4cvt + q, d = reg
        size_t addr = ((size_t)(b * CH + 32 * cvh + 4 * cvt + q) * NN
                       + (r0 + 16 * w + l15)) * 4;
        float4 xr = *(const float4*)(x3d + addr);
        float4 res;
        res.x = fmaf(gl, o[0], xr.x);
        res.y = fmaf(gl, o[1], xr.y);
        res.z = fmaf(gl, o[2], xr.z);
        res.w = fmaf(gl, o[3], xr.w);
        *(float4*)(out + addr) = res;
    }
}

extern "C" void kernel_launch(void* const* d_in, const int* in_sizes, int n_in,
                              void* d_out, int out_size, void* d_ws, size_t ws_size,
                              hipStream_t stream)
{
    const float* x2d = (const float*)d_in[0];
    const float* x3d = (const float*)d_in[1];
    const float* Wq  = (const float*)d_in[2];
    const float* bq  = (const float*)d_in[3];
    const float* Wk  = (const float*)d_in[4];
    const float* bk  = (const float*)d_in[5];
    const float* Wv  = (const float*)d_in[6];
    const float* bv  = (const float*)d_in[7];
    const float* gma = (const float*)d_in[8];

    ushort* wsb = (ushort*)d_ws;

    qkv_kernel<<<512, 256, 0, stream>>>(x2d, Wq, bq, Wk, bk, Wv, bv,
                                        wsb + QB_OFF, wsb + KB_OFF, wsb + VT_OFF);
    flash_kernel<<<512, 256, 0, stream>>>(wsb + QB_OFF, wsb + KB_OFF, wsb + VT_OFF,
                                          x3d, gma, (float*)d_out);
}

// Round 11
// 169.072 us; speedup vs baseline: 3.0633x; 1.0145x over previous
//
#include <hip/hip_runtime.h>
#include <hip/hip_bf16.h>

// B=4, C=64, H=W=64, D=4, CQ=8. N=H*W=4096, f_qk=32, f_v=256. I/O fp32.
// R11 = R10 with qkv compute restructured to avoid register-array spill:
// R10's dots<NO> held V[20]+A[8]+xr[64] > the 80-VGPR allocation -> scratch
// spill in the inner loop (VALUBusy 7.6%, 99 us). Now outputs are computed
// in PAIRS (2 accs, stored to LDS immediately) like R2's 13-us structure,
// keeping live set ~= xr[64]+2+addr. Flash unchanged from R10 (passing,
// no spill: global_load_lds V staging, K-pair 16x16x32 PV, P in regs).
#define CH 64
#define NN 4096
#define SS 16384

typedef __attribute__((ext_vector_type(8))) short bf16x8;
typedef __attribute__((ext_vector_type(4))) float f32x4;

// ws layout (ushort elems): Qb (B,N,32) | Kb (B,N,32) |
// Vt [b][sup:32][cv:256][slot:144] (128 data slots + 16 pad)
#define QB_OFF 0
#define KB_OFF 524288
#define VT_OFF 1048576

static __device__ __forceinline__ ushort bfbits(float x) {
    __hip_bfloat16 h = __float2bfloat16(x);
    return *(ushort*)&h;
}

static __device__ __forceinline__ void gld_lds16(const ushort* g, ushort* l) {
    __builtin_amdgcn_global_load_lds(
        (const __attribute__((address_space(1))) void*)g,
        (__attribute__((address_space(3))) void*)l, 16, 0, 0);
}

// ---------------- qkv ----------------
// grid 512 = (b, sup in [0,32), og in [0,4)). 256 threads = (nl = tid>>2, d).
// Block covers both 64-n tiles of super-tile sup (t = 0,1), og splits outputs:
// og0: q8 + v[0:12); og1: k8 + v[12:24); og2: v[24:44); og3: v[44:64).
// Outputs computed in pairs; each result goes straight to the LDS transpose
// tile (live regs ~= xr[64] + 2 accs -> no spill).
__global__ __launch_bounds__(256) void qkv_kernel(
    const float* __restrict__ x,
    const float* __restrict__ Wq, const float* __restrict__ bq,
    const float* __restrict__ Wk, const float* __restrict__ bk,
    const float* __restrict__ Wv, const float* __restrict__ bv,
    ushort* __restrict__ qb, ushort* __restrict__ kb, ushort* __restrict__ vt)
{
    __shared__ __align__(16) ushort Tqk[128 * 40];  // [n_loc][f], q or k
    __shared__ __align__(16) ushort Tv[80 * 144];   // [cv_loc][slot]

    const int blk = blockIdx.x;
    const int b = blk >> 7, sup = (blk >> 2) & 31, og = blk & 3;
    const int tid = threadIdx.x;
    const int nl = tid >> 2, d = tid & 3;

    const int vcnt = (og < 2) ? 12 : 20;
    const int vo0 = (og == 0) ? 0 : (og == 1) ? 12 : (og == 2) ? 24 : 44;

    const float* xb = x + (size_t)b * CH * SS + sup * 512;

    for (int t = 0; t < 2; ++t) {
        const float* xp = xb + t * 256 + tid;
        float xr[CH];
#pragma unroll
        for (int c = 0; c < CH; ++c) xr[c] = xp[(size_t)c * SS];

        // flash pair-interleave: m_loc = nl of tile t -> slot
        const int slot = 32 * (nl >> 4) + 8 * ((nl >> 2) & 3) + 4 * t + (nl & 3);

        if (og < 2) {
            const float* Wqk = (og == 0) ? Wq : Wk;
            const float* bqk = (og == 0) ? bq : bk;
            ushort* trow = &Tqk[(t * 64 + nl) * 40 + d];
#pragma unroll
            for (int o = 0; o < 8; o += 2) {
                float a0 = bqk[o], a1 = bqk[o + 1];
#pragma unroll
                for (int c = 0; c < CH; ++c) {
                    a0 = fmaf(Wqk[o * CH + c],       xr[c], a0);
                    a1 = fmaf(Wqk[(o + 1) * CH + c], xr[c], a1);
                }
                trow[o * 4]       = bfbits(a0);
                trow[(o + 1) * 4] = bfbits(a1);
            }
        }
        ushort* vcol = &Tv[d * 144 + slot];
        const float* Wvb = Wv + vo0 * CH;
        const float* bvb = bv + vo0;
        if (og < 2) {
#pragma unroll
            for (int j = 0; j < 12; j += 2) {
                float a0 = bvb[j], a1 = bvb[j + 1];
#pragma unroll
                for (int c = 0; c < CH; ++c) {
                    a0 = fmaf(Wvb[j * CH + c],       xr[c], a0);
                    a1 = fmaf(Wvb[(j + 1) * CH + c], xr[c], a1);
                }
                vcol[(j * 4) * 144]       = bfbits(a0);
                vcol[((j + 1) * 4) * 144] = bfbits(a1);
            }
        } else {
#pragma unroll
            for (int j = 0; j < 20; j += 2) {
                float a0 = bvb[j], a1 = bvb[j + 1];
#pragma unroll
                for (int c = 0; c < CH; ++c) {
                    a0 = fmaf(Wvb[j * CH + c],       xr[c], a0);
                    a1 = fmaf(Wvb[(j + 1) * CH + c], xr[c], a1);
                }
                vcol[(j * 4) * 144]       = bfbits(a0);
                vcol[((j + 1) * 4) * 144] = bfbits(a1);
            }
        }
    }
    __syncthreads();

    // Q/K readout: 128 rows x 32 ushorts = 512 uint4 chunks, 2 per thread
    if (og < 2) {
        ushort* dst = (og == 0 ? qb : kb);
#pragma unroll
        for (int jj = 0; jj < 2; ++jj) {
            int idx = jj * 256 + tid;
            int row = idx >> 2, seg = idx & 3;
            *(uint4*)(dst + ((size_t)(b * NN + sup * 128 + row)) * 32 + seg * 8)
                = *(const uint4*)&Tqk[row * 40 + seg * 8];
        }
    }
    // V readout: vcnt*4 rows x 128 data slots = vcnt*64 uint4 chunks
    const int nchunks = vcnt * 64;   // 768 (og<2) or 1280 (og>=2)
    ushort* vout = vt + ((size_t)((b * 32 + sup) * 256 + vo0 * 4)) * 144;
#pragma unroll
    for (int j = 0; j < 5; ++j) {
        int idx = j * 256 + tid;
        if (idx < nchunks) {
            int row = idx >> 4, seg = idx & 15;
            *(uint4*)(vout + (size_t)row * 144 + seg * 8)
                = *(const uint4*)&Tv[row * 144 + seg * 8];
        }
    }
}

// ---------------- flash ----------------
// grid 512 = (b, 64-row Q-tile, cv-half). 256 threads = 4 waves.
// Wave w owns m-slice [16w,16w+16) of each 64-m tile; pair = 2 tiles = 32 k.
// V staged async global->LDS (no VGPRs); K 1-pair-ahead register prefetch.
__global__ __launch_bounds__(256, 2) void flash_kernel(
    const ushort* __restrict__ qb, const ushort* __restrict__ kb,
    const ushort* __restrict__ vt, const float* __restrict__ x3d,
    const float* __restrict__ gptr, float* __restrict__ out)
{
    __shared__ __align__(16) ushort Vls[2][128 * 144];  // [cv'][slot], dbuf
    __shared__ float lbuf[4 * 4 * 16];

    const int tid = threadIdx.x;
    const int b   = blockIdx.x >> 7;
    const int rem = blockIdx.x & 127;
    const int r0  = (rem >> 1) << 6;
    const int cvh = rem & 1;
    const int w = tid >> 6, lane = tid & 63, q = lane >> 4, l15 = lane & 15;

    // Q B-frags (16x16x32): B[f=8q+j][r=16rt+l15]
    bf16x8 Qf[4];
#pragma unroll
    for (int rt = 0; rt < 4; ++rt)
        Qf[rt] = *(const bf16x8*)(qb + (size_t)(b * NN + r0 + 16 * rt + l15) * 32 + 8 * q);

    f32x4 acc[8][4];
#pragma unroll
    for (int i = 0; i < 8; ++i)
#pragma unroll
        for (int j = 0; j < 4; ++j) acc[i][j] = (f32x4){0.f, 0.f, 0.f, 0.f};
    float l_acc[4] = {0.f, 0.f, 0.f, 0.f};

    // K rows for wave w, tile mt: kb[(mt*64 + 16w + l15)*32 + 8q]
    const ushort* kgl = kb + (size_t)b * NN * 32 + (16 * w + l15) * 32 + 8 * q;

    // V stream: block's 128-cv half of each sup = 128*144 ushorts contiguous
    const ushort* vgl = vt + ((size_t)(b * 32) * 256 + 128 * cvh) * 144;

    // async stage pair 0 -> buf 0 (wave-uniform base + lane*16: valid DMA)
#pragma unroll
    for (int i = 0; i < 9; ++i)
        gld_lds16(vgl + (size_t)(i * 256 + tid) * 8,
                  (ushort*)Vls[0] + (i * 256 + tid) * 8);

    bf16x8 Kn0 = *(const bf16x8*)(kgl);
    bf16x8 Kn1 = *(const bf16x8*)(kgl + 2048);

    for (int pt = 0; pt < 32; ++pt) {
        __syncthreads();   // vmcnt drained: buf[pt&1] DMA landed; buf[pt^1] readers done
        if (pt < 31) {     // async prefetch pair pt+1 into the other buffer
            const ushort* src = vgl + (size_t)(pt + 1) * 36864;
            ushort* dst = (ushort*)Vls[(pt + 1) & 1];
#pragma unroll
            for (int i = 0; i < 9; ++i)
                gld_lds16(src + (size_t)(i * 256 + tid) * 8, dst + (i * 256 + tid) * 8);
        }
        bf16x8 Ka0 = Kn0, Ka1 = Kn1;   // loaded last iter, resolved by barrier
        if (pt < 31) {
            Kn0 = *(const bf16x8*)(kgl + (size_t)(2 * pt + 2) * 2048);
            Kn1 = *(const bf16x8*)(kgl + (size_t)(2 * pt + 3) * 2048);
        }

        // S^T slices: D[m=4q+reg][r=16rt+l15] for tiles 0,1 of the pair
        f32x4 S0[4], S1[4];
#pragma unroll
        for (int rt = 0; rt < 4; ++rt)
            S0[rt] = __builtin_amdgcn_mfma_f32_16x16x32_bf16(
                Ka0, Qf[rt], (f32x4){0.f, 0.f, 0.f, 0.f}, 0, 0, 0);
#pragma unroll
        for (int rt = 0; rt < 4; ++rt)
            S1[rt] = __builtin_amdgcn_mfma_f32_16x16x32_bf16(
                Ka1, Qf[rt], (f32x4){0.f, 0.f, 0.f, 0.f}, 0, 0, 0);

        // exp (no max-sub: |s| <~ 9); concat pair C-layouts -> 16x16x32 B-frag
        bf16x8 Pb[4];
#pragma unroll
        for (int rt = 0; rt < 4; ++rt) {
            float e0 = __expf(S0[rt][0]), e1 = __expf(S0[rt][1]);
            float e2 = __expf(S0[rt][2]), e3 = __expf(S0[rt][3]);
            float f0 = __expf(S1[rt][0]), f1 = __expf(S1[rt][1]);
            float f2 = __expf(S1[rt][2]), f3 = __expf(S1[rt][3]);
            l_acc[rt] += ((e0 + e1) + (e2 + e3)) + ((f0 + f1) + (f2 + f3));
            bf16x8 p;
            p[0] = (short)bfbits(e0); p[1] = (short)bfbits(e1);
            p[2] = (short)bfbits(e2); p[3] = (short)bfbits(e3);
            p[4] = (short)bfbits(f0); p[5] = (short)bfbits(f1);
            p[6] = (short)bfbits(f2); p[7] = (short)bfbits(f3);
            Pb[rt] = p;
        }

        // PV: A[cv=16cvt+l15][k=8q+j] = one ds_read_b128 (slots 32w+8q..+7)
        const ushort* vb = Vls[pt & 1] + 32 * w + 8 * q;
#pragma unroll
        for (int cvt = 0; cvt < 8; ++cvt) {
            bf16x8 Va = *(const bf16x8*)(vb + (16 * cvt + l15) * 144);
#pragma unroll
            for (int rt = 0; rt < 4; ++rt)
                acc[cvt][rt] = __builtin_amdgcn_mfma_f32_16x16x32_bf16(
                    Va, Pb[rt], acc[cvt][rt], 0, 0, 0);
        }
    }

    // l: reduce over quads (shfl) then across 4 waves (lbuf)
#pragma unroll
    for (int rt = 0; rt < 4; ++rt) {
        float v = l_acc[rt];
        v += __shfl_xor(v, 16);
        v += __shfl_xor(v, 32);
        if (lane < 16) lbuf[(w * 4 + rt) * 16 + lane] = v;
    }
    __syncthreads();
    // this thread's epilogue rows are r = 16w + l15 (rt = w)
    const float linv = 1.f / (lbuf[(0 + w) * 16 + l15] + lbuf[(4 + w) * 16 + l15] +
                              lbuf[(8 + w) * 16 + l15] + lbuf[(12 + w) * 16 + l15]);
    const float gl = gptr[0] * linv;

    // cross-wave O reduction in 8 cvt chunks; Obuf aliases Vls[0]
    f32x4* Obuf = (f32x4*)&Vls[0][0];
#pragma unroll
    for (int cvt = 0; cvt < 8; ++cvt) {
        __syncthreads();
#pragma unroll
        for (int rt = 0; rt < 4; ++rt)
            Obuf[(w * 64 + lane) * 5 + rt] = acc[cvt][rt];
        __syncthreads();
        f32x4 o = Obuf[lane * 5 + w];
        o += Obuf[(64 + lane) * 5 + w];
        o += Obuf[(128 + lane) * 5 + w];
        o += Obuf[(192 + lane) * 5 + w];
        // cv = 128cvh + 16cvt + 4q + reg -> c = 32cvh + 4cvt + q, d = reg
        size_t addr = ((size_t)(b * CH + 32 * cvh + 4 * cvt + q) * NN
                       + (r0 + 16 * w + l15)) * 4;
        float4 xr = *(const float4*)(x3d + addr);
        float4 res;
        res.x = fmaf(gl, o[0], xr.x);
        res.y = fmaf(gl, o[1], xr.y);
        res.z = fmaf(gl, o[2], xr.z);
        res.w = fmaf(gl, o[3], xr.w);
        *(float4*)(out + addr) = res;
    }
}

extern "C" void kernel_launch(void* const* d_in, const int* in_sizes, int n_in,
                              void* d_out, int out_size, void* d_ws, size_t ws_size,
                              hipStream_t stream)
{
    const float* x2d = (const float*)d_in[0];
    const float* x3d = (const float*)d_in[1];
    const float* Wq  = (const float*)d_in[2];
    const float* bq  = (const float*)d_in[3];
    const float* Wk  = (const float*)d_in[4];
    const float* bk  = (const float*)d_in[5];
    const float* Wv  = (const float*)d_in[6];
    const float* bv  = (const float*)d_in[7];
    const float* gma = (const float*)d_in[8];

    ushort* wsb = (ushort*)d_ws;

    qkv_kernel<<<512, 256, 0, stream>>>(x2d, Wq, bq, Wk, bk, Wv, bv,
                                        wsb + QB_OFF, wsb + KB_OFF, wsb + VT_OFF);
    flash_kernel<<<512, 256, 0, stream>>>(wsb + QB_OFF, wsb + KB_OFF, wsb + VT_OFF,
                                          x3d, gma, (float*)d_out);
}